// Round 1
// baseline (637.907 us; speedup 1.0000x reference)
//
#include <hip/hip_runtime.h>

// LIF scan: B=16, S=256, H=128, N=64. T = S*H = 32768 sequential steps per
// (b,n) chain; 1024 chains. Bit-exactness with the fp32 sequential reference
// required -> add chain cannot be reassociated. Chain form (proven bit-exact):
//     s' = prev ? x : fl(s + x);  prev' = s' > th
//
// R8: two changes, one per pass.
//  pass1: R7's 4-buffer VGPR pipeline was collapsed by the register
//    allocator (VGPR_Count=136 < the 256+ the pipeline needs) -> effective
//    lookahead ~96 steps < ~900cyc HBM latency (FETCH shows half the x
//    stream misses L2) -> vmcnt stalls = the 24.3 cyc/step. Replace with
//    LDS-resident x: stage 32KB quarters (reg->ds_write, serial, ~3us
//    total), consume via wave-uniform ds_read_b128 (broadcast, conflict
//    free, latency hidden by compiler's counted lgkmcnt). Main loop has no
//    vmcnt dependence at all. Target ~10-14 cyc/step.
//  pass2: (a) LDS 33.3KB->16.6KB (two 64-step halves) lifts residency
//    4->9 blocks/CU; (b) drop nontemporal stores -- nt bypasses L2 so store
//    retirement is paced by HBM per-wave; plain stores complete into L2 and
//    drain asynchronously; (c) read mapping now 2-way bank-free.
//    Checkpoint format and replay math unchanged (bit-exact).

namespace {
constexpr int kB = 16;
constexpr int kS = 256;
constexpr int kH = 128;
constexpr int kN = 64;
constexpr int kT = kS * kH;                 // 32768
constexpr long kPerB = (long)kS * kN * kH;  // 2,097,152 per batch per tensor
constexpr int kQ = 8192;                    // steps per staged quarter
constexpr size_t kWsS = (size_t)kB * kS * kN * sizeof(float);          // 1 MB
constexpr size_t kWsM = (size_t)kB * kS * sizeof(unsigned long long);  // 32 KB
}

typedef float v4f __attribute__((ext_vector_type(4)));

// Opaque VGPR zero: defeats uniform-scalarization so wave-uniform-looking
// loads use the vector path (vmcnt, in-order) instead of SMEM s_loads
// (lgkmcnt, unordered -> full drains). Proven effective in R6.
__device__ __forceinline__ int opaque_vgpr_zero() {
  int z;
  asm volatile("v_mov_b32 %0, 0" : "=v"(z));
  return z;
}

// ---------------------------------------------------------------------------
// Pass 1: the sequential chains. block = batch, lane = neuron. x staged into
// LDS one 32KB quarter at a time; consume loop is pure VALU + uniform
// ds_read_b128. Checkpoints (entering-state s + prev ballot) at every row.
// ---------------------------------------------------------------------------
__global__ __launch_bounds__(64, 1) void lif_pass1_kernel(
    const float* __restrict__ x, const float* __restrict__ thresh,
    const float* __restrict__ acc0, float* __restrict__ ckpt_s,
    unsigned long long* __restrict__ ckpt_m) {
  const int b = blockIdx.x;
  const int lane = threadIdx.x;
  const float th = thresh[lane];

  __shared__ v4f xs[kQ / 4];  // 32 KB: one quarter of this batch's x stream

  const v4f* __restrict__ xg =
      (const v4f*)(x + (long)b * kT) + opaque_vgpr_zero();

  float s = acc0[b * kN + lane];
  bool prev = false;

  float* __restrict__ cs = ckpt_s + (long)b * kS * kN + lane;
  unsigned long long* __restrict__ cm = ckpt_m + (long)b * kS;

  for (int q = 0; q < 4; ++q) {
    // ---- stage quarter q: 2048 v4f = 32 wave-instrs of 1 KB each.
    // Two separate unrolled loops keep all 32 loads in flight (pipelined
    // counted-vmcnt drain), then 32 contiguous ds_write_b128.
    {
      const v4f* __restrict__ src = xg + (long)q * (kQ / 4) + lane;
      v4f tmp[32];
#pragma unroll
      for (int i = 0; i < 32; ++i) tmp[i] = src[i * 64];
#pragma unroll
      for (int i = 0; i < 32; ++i) xs[i * 64 + lane] = tmp[i];
    }
    // Single wave: DS pipe is in-order per wave; ds_reads below see the
    // ds_writes above without a barrier.

    // ---- consume: 64 rows of 128 steps each
    for (int jrow = 0; jrow < 64; ++jrow) {
      const int r = q * 64 + jrow;
      cs[(long)r * kN] = s;  // checkpoint entering state
      {
        const unsigned long long m = __ballot(prev);
        if (lane == 0) cm[r] = m;
      }
      const v4f* __restrict__ xr = &xs[jrow * 32];
#pragma unroll
      for (int k = 0; k < 32; ++k) {
        const v4f xv = xr[k];  // uniform ds_read_b128 (broadcast, no conflict)
#pragma unroll
        for (int j = 0; j < 4; ++j) {
          const float xt = xv[j];
          const float u = s + xt;  // dep-chain op 1
          s = prev ? xt : u;       // dep-chain op 2 (cndmask)
          prev = s > th;           // off-chain cmp
        }
      }
    }
  }
}

// ---------------------------------------------------------------------------
// Pass 2: replay + dense coalesced write. One wave per (b,row); lane = n.
// Bit-identical replay from checkpoint; ov staged in LDS per 64-step half
// (16.6 KB -> 9 blocks/CU); flush as plain (L2-completing) 1 KB wave stores.
// spike = ov > 0. Single-wave block: DS in-order, no barriers.
// ---------------------------------------------------------------------------
__global__ __launch_bounds__(64, 2) void lif_pass2_kernel(
    const float* __restrict__ x, const float* __restrict__ thresh,
    const float* __restrict__ ckpt_s,
    const unsigned long long* __restrict__ ckpt_m, float* __restrict__ out) {
  const int wid = blockIdx.x;
  const int b = wid >> 8;
  const int srow = wid & 255;
  const int lane = threadIdx.x;

  __shared__ float ov[kH / 2][kN + 1];  // 16.6 KB

  const v4f* __restrict__ xr4 =
      (const v4f*)(x + (long)b * kT + srow * kH) + opaque_vgpr_zero();

  v4f xb[32];
#pragma unroll
  for (int i = 0; i < 32; ++i) xb[i] = xr4[i];  // 32 loads in flight

  const float th = thresh[lane];
  float s = ckpt_s[((long)b * kS + srow) * kN + lane];
  bool prev = (ckpt_m[b * kS + srow] >> lane) & 1ULL;

  float* __restrict__ obase = out + (long)b * kPerB + (long)srow * (kN * kH);
  float* __restrict__ sbase = obase + (long)kB * kPerB;

#pragma unroll
  for (int half = 0; half < 2; ++half) {
    // ---- replay 64 steps into LDS (write banks: (hh+n)%32 -> 2-way, free)
#pragma unroll
    for (int hh = 0; hh < kH / 2; ++hh) {
      const int h = half * (kH / 2) + hh;
      const float xt = xb[h >> 2][h & 3];
      const float u = s + xt;
      s = prev ? xt : u;  // bit-identical replay
      prev = s > th;
      ov[hh][lane] = prev ? s : 0.0f;
    }
    // ---- flush: lane covers (n = 4i + lane>>4, h-quad q = lane&15).
    // LDS read banks: (4(q&7) + nsub)%32 -> 2-way, free. Stores: 4 rows of
    // 256 B contiguous per instr = 1 KB/wave.
    const int q = lane & 15;
    const int nsub = lane >> 4;
    const int h0 = half * (kH / 2) + q * 4;
#pragma unroll
    for (int i = 0; i < 16; ++i) {
      const int n = i * 4 + nsub;
      v4f o, sp;
#pragma unroll
      for (int j = 0; j < 4; ++j) {
        const float v = ov[q * 4 + j][n];
        o[j] = v;
        sp[j] = v > 0.0f ? 1.0f : 0.0f;
      }
      *(v4f*)(obase + (long)n * kH + h0) = o;
      *(v4f*)(sbase + (long)n * kH + h0) = sp;
    }
    // next half's ds_writes are ordered after these ds_reads (in-order DS
    // pipe) -> no WAR hazard.
  }
}

// ---------------------------------------------------------------------------
// Fallback (ws too small): R4's passing fused kernel (unchanged).
// ---------------------------------------------------------------------------
__global__ __launch_bounds__(128) void lif_fused_kernel(
    const float* __restrict__ x, const float* __restrict__ thresh,
    const float* __restrict__ acc0, float* __restrict__ out) {
  const int bid = blockIdx.x;
  const int b = bid >> 2;
  const int ng = bid & 3;
  const int tid = threadIdx.x;
  const int wave = tid >> 6;
  const int lane = tid & 63;
  __shared__ float buf[2][kH][64];
  const float* __restrict__ xb = x + (long)b * kT;
  float* __restrict__ outs_g = out + (long)b * kPerB + (long)(ng * 16) * kH;
  float* __restrict__ spks_g = outs_g + (long)kB * kPerB;
  if (wave == 0) {
    const int n = lane & 15;
    const float th = thresh[ng * 16 + n];
    float s = acc0[b * kN + ng * 16 + n];
    bool prev = false;
    for (int r = 0; r < kS + 1; ++r) {
      if (r < kS) {
        float* __restrict__ bk = &buf[r & 1][0][lane];
        const float* __restrict__ xr = xb + r * kH;
#pragma unroll
        for (int k = 0; k < kH; ++k) {
          const float xt = xr[k];
          const float u = s + xt;
          s = prev ? xt : u;
          prev = s > th;
          bk[k * 64] = s;
        }
      }
      __syncthreads();
    }
  } else {
    const int n = lane >> 2;
    const int hg = lane & 3;
    const float th = thresh[ng * 16 + n];
    for (int r = 0; r < kS + 1; ++r) {
      if (r > 0) {
        const int rr = r - 1;
        const float(*bk)[64] = buf[rr & 1];
        float* __restrict__ orow = outs_g + (long)rr * (kN * kH) + n * kH;
        float* __restrict__ srow = spks_g + (long)rr * (kN * kH) + n * kH;
#pragma unroll
        for (int i = 0; i < 8; ++i) {
          const int hh = hg * 4 + i * 16;
          v4f ovv, sv;
#pragma unroll
          for (int j = 0; j < 4; ++j) {
            const float v = bk[hh + j][n];
            const bool sp = v > th;
            ovv[j] = sp ? v : 0.0f;
            sv[j] = sp ? 1.0f : 0.0f;
          }
          *(v4f*)(orow + hh) = ovv;
          *(v4f*)(srow + hh) = sv;
        }
      }
      __syncthreads();
    }
  }
}

// ---------------------------------------------------------------------------
extern "C" void kernel_launch(void* const* d_in, const int* in_sizes, int n_in,
                              void* d_out, int out_size, void* d_ws, size_t ws_size,
                              hipStream_t stream) {
  const float* inputs = (const float*)d_in[0];    // [B,S,H] fp32
  const float* threshes = (const float*)d_in[1];  // [N] fp32
  const float* acc0 = (const float*)d_in[2];      // [B,N] fp32
  float* out = (float*)d_out;

  if (ws_size >= kWsS + kWsM) {
    float* ckpt_s = (float*)d_ws;
    unsigned long long* ckpt_m = (unsigned long long*)((char*)d_ws + kWsS);
    lif_pass1_kernel<<<kB, kN, 0, stream>>>(inputs, threshes, acc0, ckpt_s,
                                            ckpt_m);
    lif_pass2_kernel<<<kB * kS, kN, 0, stream>>>(inputs, threshes, ckpt_s,
                                                 ckpt_m, out);
  } else {
    lif_fused_kernel<<<kB * 4, 128, 0, stream>>>(inputs, threshes, acc0, out);
  }
}